// Round 1
// baseline (172.785 us; speedup 1.0000x reference)
//
#include <hip/hip_runtime.h>

#define OBS 128
#define ACTD 32
#define DIMX 160
#define HID 64
#define NBATCH 32768
#define TMAXX 8
#define CTR 7
#define NPOS 15

typedef short bf16x8 __attribute__((ext_vector_type(8)));
typedef float f32x4 __attribute__((ext_vector_type(4)));

#define MFMA(a,b,c) __builtin_amdgcn_mfma_f32_16x16x32_bf16((a),(b),(c),0,0,0)

// ws layout (bytes):
//   [0, 4*NBATCH)        len_f  (int32 per element)
//   [4*NBATCH, 8*NBATCH) len_b
//   [8*NBATCH, ...)      bf16 weights, element offsets below
#define WOFF_WIHF 0
#define WOFF_WHHF 30720
#define WOFF_WIHB 43008
#define WOFF_WHHB 73728
#define WOFF_MW1  86016
#define WOFF_MW2  94208
#define WOFF_MUW  98304
#define WOFF_LVW  102400
#define WTOTAL    106496

__device__ __forceinline__ unsigned short f2bf(float f) {
  unsigned u = __float_as_uint(f);
  return (unsigned short)((u + 0x7FFFu + ((u >> 16) & 1u)) >> 16);
}

__device__ __forceinline__ float wsum(float v) {
#pragma unroll
  for (int s = 1; s < 64; s <<= 1) v += __shfl_xor(v, s);
  return v;
}
__device__ __forceinline__ float wmax(float v) {
#pragma unroll
  for (int s = 1; s < 64; s <<= 1) v = fmaxf(v, __shfl_xor(v, s));
  return v;
}

// ---------------- prep: convert weights to bf16 in ws ----------------
__global__ __launch_bounds__(256) void k_prep(
    const float* __restrict__ a0, const float* __restrict__ a1,
    const float* __restrict__ a2, const float* __restrict__ a3,
    const float* __restrict__ a4, const float* __restrict__ a5,
    const float* __restrict__ a6, const float* __restrict__ a7,
    unsigned short* __restrict__ dst) {
  int i = blockIdx.x * 256 + threadIdx.x;
  if (i >= WTOTAL) return;
  int j = i;
  const float* s;
  if (j < 30720) { s = a0; }
  else if ((j -= 30720) < 12288) { s = a1; }
  else if ((j -= 12288) < 30720) { s = a2; }
  else if ((j -= 30720) < 12288) { s = a3; }
  else if ((j -= 12288) < 8192)  { s = a4; }
  else if ((j -= 8192) < 4096)   { s = a5; }
  else if ((j -= 4096) < 4096)   { s = a6; }
  else { j -= 4096; s = a7; }
  dst[i] = f2bf(s[j]);
}

// ---------------- decide: features -> MLP -> argmax -> lens ----------------
__global__ __launch_bounds__(256) void k_decide(
    const float* __restrict__ obs, const float* __restrict__ act,
    const float* __restrict__ ln_g, const float* __restrict__ ln_b,
    const float* __restrict__ dw1, const float* __restrict__ db1,
    const float* __restrict__ dw2, const float* __restrict__ db2,
    const float* __restrict__ dw3, const float* __restrict__ db3,
    int* __restrict__ lens) {
  int b = blockIdx.x * 4 + (threadIdx.x >> 6);
  int l = threadIdx.x & 63;
  const float* o7 = obs + ((size_t)b * NPOS + CTR) * OBS;
  const float* o6 = o7 - OBS;
  const float* o5 = o7 - 2 * OBS;
  const float* o4 = o7 - 3 * OBS;
  float x0 = o7[l], x1 = o7[l + 64];
  float y60 = o6[l], y61 = o6[l + 64];
  float y50 = o5[l], y51 = o5[l + 64];
  float y40 = o4[l], y41 = o4[l + 64];
  float ap = (l < 32) ? act[((size_t)b * NPOS + 6) * ACTD + l] : 0.0f;

  // entropy of softmax(obs_t)
  float m = wmax(fmaxf(x0, x1));
  float e0 = expf(x0 - m), e1 = expf(x1 - m);
  float s = wsum(e0 + e1);
  float inv = 1.0f / s;
  float p0 = e0 * inv, p1 = e1 * inv;
  float ent = -wsum(p0 * logf(p0 + 1e-8f) + p1 * logf(p1 + 1e-8f));

  // roc
  float d0 = wsum((x0 - y60) * (x0 - y60) + (x1 - y61) * (x1 - y61));
  float d1 = wsum((y60 - y50) * (y60 - y50) + (y61 - y51) * (y61 - y51));
  float d2 = wsum((y50 - y40) * (y50 - y40) + (y51 - y41) * (y51 - y41));
  float roc = (sqrtf(d0) + sqrtf(d1) + sqrtf(d2)) / 3.0f;

  // corr
  float sop = wsum(x0 + x1);
  float sop2 = wsum(x0 * x0 + x1 * x1);
  float sap = wsum(ap);
  float sap2 = wsum(ap * ap);
  float dotoa = wsum(ap * x0);
  float mo = sop / 128.0f, ma = sap / 128.0f;
  float num = dotoa - 128.0f * mo * ma;
  float oc2 = fmaxf(sop2 - 128.0f * mo * mo, 0.0f);
  float ac2 = fmaxf(sap2 - 128.0f * ma * ma, 0.0f);
  float corr = num / (sqrtf(oc2) * sqrtf(ac2) + 1e-8f);

  // layernorm over 3 features
  float f0 = ent, f1 = roc, f2 = corr;
  float mean = (f0 + f1 + f2) / 3.0f;
  float v0 = f0 - mean, v1 = f1 - mean, v2 = f2 - mean;
  float var = (v0 * v0 + v1 * v1 + v2 * v2) / 3.0f;
  float sd = sqrtf(var + 1e-5f);
  float fn0 = v0 / sd * ln_g[0] + ln_b[0];
  float fn1 = v1 / sd * ln_g[1] + ln_b[1];
  float fn2 = v2 / sd * ln_g[2] + ln_b[2];

  // MLP 3->16->8->14 (fp32, replicated on all lanes)
  float h1[16];
#pragma unroll
  for (int i = 0; i < 16; i++) {
    float a = db1[i] + fn0 * dw1[i * 3] + fn1 * dw1[i * 3 + 1] + fn2 * dw1[i * 3 + 2];
    h1[i] = fmaxf(a, 0.0f);
  }
  float h2[8];
#pragma unroll
  for (int i = 0; i < 8; i++) {
    float a = db2[i];
#pragma unroll
    for (int j = 0; j < 16; j++) a += h1[j] * dw2[i * 16 + j];
    h2[i] = fmaxf(a, 0.0f);
  }
  float best = -3.0e38f;
  int bi = 0;
#pragma unroll
  for (int i = 0; i < 14; i++) {
    float a = db3[i];
#pragma unroll
    for (int j = 0; j < 8; j++) a += h2[j] * dw3[i * 8 + j];
    if (a > best) { best = a; bi = i; }
  }
  int wl = bi + 2;
  int lf = (wl - 1) / 2 + 1;
  int lb = wl / 2 + 1;
  if (l == 0) {
    lens[b] = lf;
    lens[NBATCH + b] = lb;
  }
}

// ---------------- main: fused bidirectional GRU + head (bf16 MFMA) ----------------
__global__ __launch_bounds__(256, 2) void k_main(
    const float* __restrict__ obs, const float* __restrict__ act,
    const int* __restrict__ lens, const unsigned short* __restrict__ wbf,
    const float* __restrict__ bih_f, const float* __restrict__ bhh_f,
    const float* __restrict__ bih_b, const float* __restrict__ bhh_b,
    const float* __restrict__ mb1, const float* __restrict__ mb2,
    const float* __restrict__ mu_b, const float* __restrict__ lv_b,
    float* __restrict__ out) {
  __shared__ unsigned short Xl[64 * 168];  // x tile, bf16, row pad 168
  __shared__ unsigned short Hl[64 * 72];   // h tile (also t1), bf16, row pad 72
  __shared__ unsigned short Cl[64 * 136];  // comb [hf|hb], bf16, row pad 136

  const int tid = threadIdx.x;
  const int w = tid >> 6;        // wave 0..3 (owns h-units 16w..16w+15)
  const int l = tid & 63;
  const int col = l & 15;        // A-row / B-col / C-col within fragment
  const int kgrp = l >> 4;       // 0..3
  const int base = blockIdx.x * 64;

  // staging identity: thread stages quarter sq of element se
  const int se = tid >> 2, sq = tid & 3;
  const int slen_f = lens[base + se];
  const int slen_b = lens[NBATCH + base + se];

  // len packs for masking: element of C-frag (m, r) is 16m + kgrp*4 + r
  unsigned lpf[4], lpb[4];
#pragma unroll
  for (int m = 0; m < 4; m++) {
    int e = base + 16 * m + kgrp * 4;
    lpf[m] = (unsigned)lens[e] | ((unsigned)lens[e + 1] << 8) |
             ((unsigned)lens[e + 2] << 16) | ((unsigned)lens[e + 3] << 24);
    lpb[m] = (unsigned)lens[NBATCH + e] | ((unsigned)lens[NBATCH + e + 1] << 8) |
             ((unsigned)lens[NBATCH + e + 2] << 16) | ((unsigned)lens[NBATCH + e + 3] << 24);
  }

  f32x4 hreg[4];
  const int gr = 16 * w + col;  // this lane's h-unit / r-gate index

  for (int d = 0; d < 2; d++) {
    const unsigned short* wih = wbf + (d ? WOFF_WIHB : WOFF_WIHF);
    const unsigned short* whh = wbf + (d ? WOFF_WHHB : WOFF_WHHF);
    const float* bih = d ? bih_b : bih_f;
    const float* bhh = d ? bhh_b : bhh_f;
    const float bias_r = bih[gr] + bhh[gr];
    const float bias_z = bih[64 + gr] + bhh[64 + gr];
    const float bias_in = bih[128 + gr];
    const float bias_hn = bhh[128 + gr];

    // weight B-fragments: lane holds W[n=gate][k = kf*32 + kgrp*8 .. +8]
    bf16x8 wr[5], wz[5], wn[5];
#pragma unroll
    for (int kf = 0; kf < 5; kf++) {
      wr[kf] = *(const bf16x8*)(wih + (size_t)gr * 160 + kf * 32 + kgrp * 8);
      wz[kf] = *(const bf16x8*)(wih + (size_t)(64 + gr) * 160 + kf * 32 + kgrp * 8);
      wn[kf] = *(const bf16x8*)(wih + (size_t)(128 + gr) * 160 + kf * 32 + kgrp * 8);
    }
    bf16x8 vr[2], vz[2], vn[2];
#pragma unroll
    for (int kh = 0; kh < 2; kh++) {
      vr[kh] = *(const bf16x8*)(whh + (size_t)gr * 64 + kh * 32 + kgrp * 8);
      vz[kh] = *(const bf16x8*)(whh + (size_t)(64 + gr) * 64 + kh * 32 + kgrp * 8);
      vn[kh] = *(const bf16x8*)(whh + (size_t)(128 + gr) * 64 + kh * 32 + kgrp * 8);
    }

    unsigned lp[4];
#pragma unroll
    for (int m = 0; m < 4; m++) lp[m] = d ? lpb[m] : lpf[m];
    const int mylen = d ? slen_b : slen_f;

    __syncthreads();  // previous dir fully done before clearing Hl
#pragma unroll
    for (int m = 0; m < 4; m++) hreg[m] = (f32x4){0.f, 0.f, 0.f, 0.f};
    for (int i = tid; i < 64 * 36; i += 256) ((unsigned*)Hl)[i] = 0u;

    for (int t = 0; t < TMAXX; t++) {
      __syncthreads();  // A: prior step compute + h-writes done; X free
      {
        // stage x_t row for element se, quarter sq (bf16 RNE)
        int pos = (d == 0) ? (CTR - mylen + 1 + t) : (CTR + mylen - 1 - t);
        const float4* po = (const float4*)(obs + ((size_t)(base + se) * NPOS + pos) * OBS) + sq * 8;
        unsigned* xd = (unsigned*)(Xl + se * 168 + sq * 32);
#pragma unroll
        for (int i = 0; i < 8; i++) {
          float4 v = po[i];
          xd[i * 2] = (unsigned)f2bf(v.x) | ((unsigned)f2bf(v.y) << 16);
          xd[i * 2 + 1] = (unsigned)f2bf(v.z) | ((unsigned)f2bf(v.w) << 16);
        }
        const float4* pa = (const float4*)(act + ((size_t)(base + se) * NPOS + pos) * ACTD) + sq * 2;
        unsigned* xa2 = (unsigned*)(Xl + se * 168 + 128 + sq * 8);
#pragma unroll
        for (int i = 0; i < 2; i++) {
          float4 v = pa[i];
          xa2[i * 2] = (unsigned)f2bf(v.x) | ((unsigned)f2bf(v.y) << 16);
          xa2[i * 2 + 1] = (unsigned)f2bf(v.z) | ((unsigned)f2bf(v.w) << 16);
        }
      }
      __syncthreads();  // B: X_t visible

      f32x4 ar[4], az[4], ain[4], ahn[4];
#pragma unroll
      for (int m = 0; m < 4; m++) {
        ar[m] = (f32x4){0.f, 0.f, 0.f, 0.f};
        az[m] = (f32x4){0.f, 0.f, 0.f, 0.f};
        ain[m] = (f32x4){0.f, 0.f, 0.f, 0.f};
        ahn[m] = (f32x4){0.f, 0.f, 0.f, 0.f};
      }
#pragma unroll
      for (int kf = 0; kf < 5; kf++) {
#pragma unroll
        for (int m = 0; m < 4; m++) {
          bf16x8 xa = *(const bf16x8*)(Xl + (col + 16 * m) * 168 + kf * 32 + kgrp * 8);
          ar[m] = MFMA(xa, wr[kf], ar[m]);
          az[m] = MFMA(xa, wz[kf], az[m]);
          ain[m] = MFMA(xa, wn[kf], ain[m]);
        }
      }
#pragma unroll
      for (int kh = 0; kh < 2; kh++) {
#pragma unroll
        for (int m = 0; m < 4; m++) {
          bf16x8 ha = *(const bf16x8*)(Hl + (col + 16 * m) * 72 + kh * 32 + kgrp * 8);
          ar[m] = MFMA(ha, vr[kh], ar[m]);
          az[m] = MFMA(ha, vz[kh], az[m]);
          ahn[m] = MFMA(ha, vn[kh], ahn[m]);
        }
      }
      __syncthreads();  // C: all Hl reads done before updating h

      // gate nonlinearities (fp32), masked update, write h (A-layout, bf16)
#pragma unroll
      for (int m = 0; m < 4; m++) {
        unsigned lpm = lp[m];
#pragma unroll
        for (int r = 0; r < 4; r++) {
          float air = ar[m][r] + bias_r;
          float aiz = az[m][r] + bias_z;
          float rg = 1.0f / (1.0f + __expf(-air));
          float zg = 1.0f / (1.0f + __expf(-aiz));
          float nn = ain[m][r] + bias_in + rg * (ahn[m][r] + bias_hn);
          float th = 1.0f - 2.0f / (1.0f + __expf(2.0f * nn));
          float hp = hreg[m][r];
          float hnew = (1.0f - zg) * th + zg * hp;
          bool vt = (unsigned)t < ((lpm >> (8 * r)) & 0xFFu);
          float hv = vt ? hnew : hp;
          hreg[m][r] = hv;
          Hl[(16 * m + kgrp * 4 + r) * 72 + gr] = f2bf(hv);
        }
      }
    }  // t

    // store this direction's final h into comb tile
#pragma unroll
    for (int m = 0; m < 4; m++) {
#pragma unroll
      for (int r = 0; r < 4; r++) {
        Cl[(16 * m + kgrp * 4 + r) * 136 + 64 * d + gr] = f2bf(hreg[m][r]);
      }
    }
  }  // d

  __syncthreads();  // comb complete

  // ---- head: t1 = relu(comb @ mw1^T + mb1) ----
  const unsigned short* w1 = wbf + WOFF_MW1;
  const unsigned short* w2 = wbf + WOFF_MW2;
  const unsigned short* wmu = wbf + WOFF_MUW;
  const unsigned short* wlv = wbf + WOFF_LVW;
  const float b1 = mb1[gr], b2v = mb2[gr], bmu = mu_b[gr], blv = lv_b[gr];

  f32x4 t1[4];
#pragma unroll
  for (int m = 0; m < 4; m++) t1[m] = (f32x4){0.f, 0.f, 0.f, 0.f};
#pragma unroll
  for (int kf = 0; kf < 4; kf++) {
    bf16x8 bw = *(const bf16x8*)(w1 + (size_t)gr * 128 + kf * 32 + kgrp * 8);
#pragma unroll
    for (int m = 0; m < 4; m++) {
      bf16x8 ca = *(const bf16x8*)(Cl + (col + 16 * m) * 136 + kf * 32 + kgrp * 8);
      t1[m] = MFMA(ca, bw, t1[m]);
    }
  }
#pragma unroll
  for (int m = 0; m < 4; m++) {
#pragma unroll
    for (int r = 0; r < 4; r++) {
      float v = fmaxf(t1[m][r] + b1, 0.0f);
      Hl[(16 * m + kgrp * 4 + r) * 72 + gr] = f2bf(v);
    }
  }
  __syncthreads();

  // zenc = t1 @ mw2^T + mb2
  f32x4 ze[4];
#pragma unroll
  for (int m = 0; m < 4; m++) ze[m] = (f32x4){0.f, 0.f, 0.f, 0.f};
#pragma unroll
  for (int kh = 0; kh < 2; kh++) {
    bf16x8 bw = *(const bf16x8*)(w2 + (size_t)gr * 64 + kh * 32 + kgrp * 8);
#pragma unroll
    for (int m = 0; m < 4; m++) {
      bf16x8 ha = *(const bf16x8*)(Hl + (col + 16 * m) * 72 + kh * 32 + kgrp * 8);
      ze[m] = MFMA(ha, bw, ze[m]);
    }
  }
#pragma unroll
  for (int m = 0; m < 4; m++) {
#pragma unroll
    for (int r = 0; r < 4; r++) {
      Xl[(16 * m + kgrp * 4 + r) * 72 + gr] = f2bf(ze[m][r] + b2v);
    }
  }
  __syncthreads();

  // mu = zenc @ mu_w^T + mu_b ; sigma = exp(0.5*(zenc @ lv_w^T + lv_b))
  f32x4 amu[4], alv[4];
#pragma unroll
  for (int m = 0; m < 4; m++) {
    amu[m] = (f32x4){0.f, 0.f, 0.f, 0.f};
    alv[m] = (f32x4){0.f, 0.f, 0.f, 0.f};
  }
#pragma unroll
  for (int kh = 0; kh < 2; kh++) {
    bf16x8 bwm = *(const bf16x8*)(wmu + (size_t)gr * 64 + kh * 32 + kgrp * 8);
    bf16x8 bwl = *(const bf16x8*)(wlv + (size_t)gr * 64 + kh * 32 + kgrp * 8);
#pragma unroll
    for (int m = 0; m < 4; m++) {
      bf16x8 za = *(const bf16x8*)(Xl + (col + 16 * m) * 72 + kh * 32 + kgrp * 8);
      amu[m] = MFMA(za, bwm, amu[m]);
      alv[m] = MFMA(za, bwl, alv[m]);
    }
  }
#pragma unroll
  for (int m = 0; m < 4; m++) {
#pragma unroll
    for (int r = 0; r < 4; r++) {
      int e = 16 * m + kgrp * 4 + r;
      float mu = amu[m][r] + bmu;
      float sg = expf(0.5f * (alv[m][r] + blv));
      size_t o = (size_t)(base + e) * HID + gr;
      out[o] = mu;                        // z
      out[(size_t)NBATCH * HID + o] = mu; // mu
      out[2 * (size_t)NBATCH * HID + o] = sg;  // sigma
    }
  }
}

extern "C" void kernel_launch(void* const* d_in, const int* in_sizes, int n_in,
                              void* d_out, int out_size, void* d_ws, size_t ws_size,
                              hipStream_t stream) {
  const float* obs = (const float*)d_in[0];
  const float* act = (const float*)d_in[1];
  const float* ln_g = (const float*)d_in[2];
  const float* ln_b = (const float*)d_in[3];
  const float* dw1 = (const float*)d_in[4];
  const float* db1 = (const float*)d_in[5];
  const float* dw2 = (const float*)d_in[6];
  const float* db2 = (const float*)d_in[7];
  const float* dw3 = (const float*)d_in[8];
  const float* db3 = (const float*)d_in[9];
  const float* Wih_f = (const float*)d_in[10];
  const float* Whh_f = (const float*)d_in[11];
  const float* bih_f = (const float*)d_in[12];
  const float* bhh_f = (const float*)d_in[13];
  const float* Wih_b = (const float*)d_in[14];
  const float* Whh_b = (const float*)d_in[15];
  const float* bih_b = (const float*)d_in[16];
  const float* bhh_b = (const float*)d_in[17];
  const float* mw1 = (const float*)d_in[18];
  const float* mb1 = (const float*)d_in[19];
  const float* mw2 = (const float*)d_in[20];
  const float* mb2 = (const float*)d_in[21];
  const float* mu_w = (const float*)d_in[22];
  const float* mu_b = (const float*)d_in[23];
  const float* lv_w = (const float*)d_in[24];
  const float* lv_b = (const float*)d_in[25];

  int* lens = (int*)d_ws;
  unsigned short* wbf = (unsigned short*)((char*)d_ws + 8 * NBATCH);

  k_prep<<<(WTOTAL + 255) / 256, 256, 0, stream>>>(Wih_f, Whh_f, Wih_b, Whh_b,
                                                   mw1, mw2, mu_w, lv_w, wbf);
  k_decide<<<NBATCH / 4, 256, 0, stream>>>(obs, act, ln_g, ln_b, dw1, db1, dw2,
                                           db2, dw3, db3, lens);
  k_main<<<NBATCH / 64, 256, 0, stream>>>(obs, act, lens, wbf, bih_f, bhh_f,
                                          bih_b, bhh_b, mb1, mb2, mu_b, lv_b,
                                          (float*)d_out);
}